// Round 1
// baseline (2816.770 us; speedup 1.0000x reference)
//
#include <hip/hip_runtime.h>
#include <math.h>

// Problem constants: B=8, N=1024, C=768, H=12, hd=64
#define Bb 8
#define Nn 1024
#define Cc 768
#define Hh 12
#define HD 64
#define LD 2304   // qkv buffer leading dim (3*C)

#define TILE 64
#define KT 16

// ---------------------------------------------------------------------------
// C = alpha * (A @ B^T)  [+ C if accum] [+ bias[col]] [+ add[row,col]]
// A: [M,K] row-major ld=lda, B: [N,K] row-major ld=ldb, C: [M,N] ld=ldc
// batch: z -> b1=z/zdiv, b2=z%zdiv; ptr += b1*s1 + b2*s2
// Requires M%64==0, N%64==0, K%16==0.
__global__ __launch_bounds__(256)
void gemm_abt(const float* __restrict__ A, int lda, long sA1, long sA2,
              const float* __restrict__ B, int ldb, long sB1, long sB2,
              float* __restrict__ C, int ldc, long sC1, long sC2,
              const float* __restrict__ add, const float* __restrict__ bias,
              int M, int N, int K, int zdiv, float alpha, int accum)
{
    int z = blockIdx.z;
    int b1 = z / zdiv, b2 = z - b1 * zdiv;
    A += (long)b1 * sA1 + (long)b2 * sA2;
    B += (long)b1 * sB1 + (long)b2 * sB2;
    long coff = (long)b1 * sC1 + (long)b2 * sC2;
    C += coff;
    if (add) add += coff;

    __shared__ float As[KT][TILE + 1];
    __shared__ float Bs[KT][TILE + 1];

    int m0 = blockIdx.x * TILE;
    int n0 = blockIdx.y * TILE;
    int tid = threadIdx.x;
    int tm = tid >> 4, tn = tid & 15;

    float acc[4][4] = {};

    for (int k0 = 0; k0 < K; k0 += KT) {
#pragma unroll
        for (int p = 0; p < 4; ++p) {
            int l = tid + 256 * p;
            int kk = l & 15, mm = l >> 4;
            As[kk][mm] = A[(long)(m0 + mm) * lda + (k0 + kk)];
            Bs[kk][mm] = B[(long)(n0 + mm) * ldb + (k0 + kk)];
        }
        __syncthreads();
#pragma unroll
        for (int k = 0; k < KT; ++k) {
            float a[4], b[4];
#pragma unroll
            for (int i = 0; i < 4; ++i) a[i] = As[k][tm + 16 * i];
#pragma unroll
            for (int j = 0; j < 4; ++j) b[j] = Bs[k][tn + 16 * j];
#pragma unroll
            for (int i = 0; i < 4; ++i)
#pragma unroll
                for (int j = 0; j < 4; ++j)
                    acc[i][j] = fmaf(a[i], b[j], acc[i][j]);
        }
        __syncthreads();
    }

#pragma unroll
    for (int i = 0; i < 4; ++i) {
        int row = m0 + tm + 16 * i;
#pragma unroll
        for (int j = 0; j < 4; ++j) {
            int col = n0 + tn + 16 * j;
            long idx = (long)row * ldc + col;
            float v = alpha * acc[i][j];
            if (accum) v += C[idx];
            if (bias) v += bias[col];
            if (add)  v += add[idx];
            C[idx] = v;
        }
    }
}

// ---------------------------------------------------------------------------
// C = alpha * (A @ B)   A: [M,K] ld=lda, B: [K,N] ld=ldb, C: [M,N] ld=ldc
__global__ __launch_bounds__(256)
void gemm_ab(const float* __restrict__ A, int lda, long sA1, long sA2,
             const float* __restrict__ B, int ldb, long sB1, long sB2,
             float* __restrict__ C, int ldc, long sC1, long sC2,
             int M, int N, int K, int zdiv, float alpha)
{
    int z = blockIdx.z;
    int b1 = z / zdiv, b2 = z - b1 * zdiv;
    A += (long)b1 * sA1 + (long)b2 * sA2;
    B += (long)b1 * sB1 + (long)b2 * sB2;
    C += (long)b1 * sC1 + (long)b2 * sC2;

    __shared__ float As[KT][TILE + 1];
    __shared__ float Bs[KT][TILE + 1];

    int m0 = blockIdx.x * TILE;
    int n0 = blockIdx.y * TILE;
    int tid = threadIdx.x;
    int tm = tid >> 4, tn = tid & 15;

    float acc[4][4] = {};

    for (int k0 = 0; k0 < K; k0 += KT) {
#pragma unroll
        for (int p = 0; p < 4; ++p) {
            int l = tid + 256 * p;
            int kk = l & 15, mm = l >> 4;
            As[kk][mm] = A[(long)(m0 + mm) * lda + (k0 + kk)];
        }
#pragma unroll
        for (int p = 0; p < 4; ++p) {
            int l = tid + 256 * p;
            int nn = l & 63, kk2 = l >> 6;
            Bs[kk2][nn] = B[(long)(k0 + kk2) * ldb + (n0 + nn)];
        }
        __syncthreads();
#pragma unroll
        for (int k = 0; k < KT; ++k) {
            float a[4], b[4];
#pragma unroll
            for (int i = 0; i < 4; ++i) a[i] = As[k][tm + 16 * i];
#pragma unroll
            for (int j = 0; j < 4; ++j) b[j] = Bs[k][tn + 16 * j];
#pragma unroll
            for (int i = 0; i < 4; ++i)
#pragma unroll
                for (int j = 0; j < 4; ++j)
                    acc[i][j] = fmaf(a[i], b[j], acc[i][j]);
        }
        __syncthreads();
    }

#pragma unroll
    for (int i = 0; i < 4; ++i) {
        int row = m0 + tm + 16 * i;
#pragma unroll
        for (int j = 0; j < 4; ++j) {
            int col = n0 + tn + 16 * j;
            C[(long)row * ldc + col] = alpha * acc[i][j];
        }
    }
}

// ---------------------------------------------------------------------------
__device__ inline float waveReduceSum(float v) {
#pragma unroll
    for (int off = 32; off; off >>= 1) v += __shfl_down(v, off, 64);
    return v;
}
__device__ inline float waveReduceMax(float v) {
#pragma unroll
    for (int off = 32; off; off >>= 1) v = fmaxf(v, __shfl_down(v, off, 64));
    return v;
}

// in-place row softmax, one block per row of 1024
__global__ __launch_bounds__(256)
void softmax_rows(float* __restrict__ p)
{
    long row = blockIdx.x;
    float* r = p + row * 1024;
    int tid = threadIdx.x;
    float4 x = ((float4*)r)[tid];
    float m = fmaxf(fmaxf(x.x, x.y), fmaxf(x.z, x.w));
    m = waveReduceMax(m);
    __shared__ float sm[4];
    __shared__ float bm, bs;
    int lane = tid & 63, wid = tid >> 6;
    if (!lane) sm[wid] = m;
    __syncthreads();
    if (tid == 0) bm = fmaxf(fmaxf(sm[0], sm[1]), fmaxf(sm[2], sm[3]));
    __syncthreads();
    float mm = bm;
    x.x = expf(x.x - mm); x.y = expf(x.y - mm);
    x.z = expf(x.z - mm); x.w = expf(x.w - mm);
    float s = x.x + x.y + x.z + x.w;
    s = waveReduceSum(s);
    if (!lane) sm[wid] = s;
    __syncthreads();
    if (tid == 0) bs = sm[0] + sm[1] + sm[2] + sm[3];
    __syncthreads();
    float inv = 1.0f / bs;
    x.x *= inv; x.y *= inv; x.z *= inv; x.w *= inv;
    ((float4*)r)[tid] = x;
}

// AH[b,i,j] = relu((AH[b,i,j]+AH[b,j,i])/2), in-place, pair-symmetric
__global__ __launch_bounds__(256)
void sym_relu(float* __restrict__ AH)
{
    long idx = (long)blockIdx.x * 256 + threadIdx.x;
    if (idx >= (long)Bb * Nn * Nn) return;
    int b = (int)(idx >> 20);
    int r = (int)(idx & 1048575);
    int i = r >> 10, j = r & 1023;
    if (j < i) return;
    float* Ab = AH + ((long)b << 20);
    float t = 0.5f * (Ab[i * 1024 + j] + Ab[j * 1024 + i]);
    t = fmaxf(t, 0.0f);
    Ab[i * 1024 + j] = t;
    Ab[j * 1024 + i] = t;
}

// dinv[b,i] = deg!=0 ? rsqrt(deg) : 0 ; deg = row sum of AH
__global__ __launch_bounds__(256)
void deg_dinv(const float* __restrict__ AH, float* __restrict__ dinv)
{
    long row = blockIdx.x;                 // 0..8191  (b*1024+i)
    const float* r = AH + row * 1024;
    int tid = threadIdx.x;
    float4 x = ((const float4*)r)[tid];
    float s = x.x + x.y + x.z + x.w;
    s = waveReduceSum(s);
    __shared__ float sm[4];
    int lane = tid & 63, wid = tid >> 6;
    if (!lane) sm[wid] = s;
    __syncthreads();
    if (tid == 0) {
        float d = sm[0] + sm[1] + sm[2] + sm[3];
        dinv[row] = (d != 0.0f) ? rsqrtf(d) : 0.0f;
    }
}

// AH[b,i,j] *= dinv[b,i]*dinv[b,j]
__global__ __launch_bounds__(256)
void scale_ah(float* __restrict__ AH, const float* __restrict__ dinv)
{
    long idx = (long)blockIdx.x * 256 + threadIdx.x;
    if (idx >= (long)Bb * Nn * Nn) return;
    int b = (int)(idx >> 20);
    int i = (int)((idx >> 10) & 1023);
    int j = (int)(idx & 1023);
    AH[idx] *= dinv[(b << 10) + i] * dinv[(b << 10) + j];
}

// circulant taps of the rfft*w->irfft gate (ortho norm, numpy c2r semantics)
__global__ void build_g(const float* __restrict__ cw, float* __restrict__ g)
{
    int d = threadIdx.x;
    if (d >= 64) return;
    float s = cw[0] + ((d & 1) ? -cw[64] : cw[64]);
#pragma unroll
    for (int f = 1; f < 32; ++f) {
        int ph = (f * d) & 63;
        float ang = 6.283185307179586f * (float)ph / 64.0f;
        s += 2.0f * (cw[2 * f] * cosf(ang) + cw[2 * f + 1] * sinf(ang));
    }
    g[d] = s * 0.015625f;   // 1/64
}

// wdiff = w_v1 - w_v2
__global__ __launch_bounds__(256)
void wdiff_k(const float* __restrict__ a, const float* __restrict__ b,
             float* __restrict__ o)
{
    int i = blockIdx.x * 256 + threadIdx.x;
    if (i < Cc * Cc) o[i] = a[i] - b[i];
}

// ifv[b,n,h*64+t] = sum_m V[b,n,h*64+m] * g[(m-t)&63], one block per (b,n)
__global__ __launch_bounds__(256)
void ifv_kernel(const float* __restrict__ qkv, const float* __restrict__ g,
                float* __restrict__ ifv)
{
    int bn = blockIdx.x;   // 0..8191
    __shared__ float Vr[768];
    __shared__ float Gs[64];
    const float* vrow = qkv + (long)bn * LD + 2 * Cc;   // V slice
    int tid = threadIdx.x;
    if (tid < 64) Gs[tid] = g[tid];
    for (int c = tid; c < 768; c += 256) Vr[c] = vrow[c];
    __syncthreads();
    for (int c = tid; c < 768; c += 256) {
        int h = c >> 6, t = c & 63;
        const float* vh = Vr + (h << 6);
        float s = 0.0f;
#pragma unroll
        for (int m2 = 0; m2 < 64; ++m2)
            s = fmaf(vh[m2], Gs[(m2 - t) & 63], s);
        ifv[(long)bn * 768 + c] = s;
    }
}

// ---------------------------------------------------------------------------
extern "C" void kernel_launch(void* const* d_in, const int* in_sizes, int n_in,
                              void* d_out, int out_size, void* d_ws, size_t ws_size,
                              hipStream_t stream)
{
    (void)in_sizes; (void)n_in; (void)out_size; (void)ws_size;

    const float* x      = (const float*)d_in[0];   // [8,1024,768]
    const float* w_qkv  = (const float*)d_in[1];   // [2304,768]
    const float* w_v1   = (const float*)d_in[2];   // [768,768]
    const float* w_v2   = (const float*)d_in[3];
    const float* w_proj = (const float*)d_in[4];
    const float* b_proj = (const float*)d_in[5];   // [768]
    const float* cw     = (const float*)d_in[6];   // [33,2]

    float* out  = (float*)d_out;                   // [8,1024,768] then attn
    float* attn = out + (long)Bb * Nn * Cc;        // [8,12,1024,1024]

    // workspace layout (floats)
    float* WS    = (float*)d_ws;
    float* QKV   = WS;                              // 8192 x 2304
    float* MV    = QKV   + (long)8192 * 2304;       // 8192 x 768
    float* IFV   = MV    + (long)8192 * 768;        // 8192 x 768
    float* OUTB  = IFV   + (long)8192 * 768;        // 8192 x 768
    float* WDIFF = OUTB  + (long)8192 * 768;        // 768 x 768
    float* DINV  = WDIFF + (long)768 * 768;         // 8192
    float* G     = DINV  + 8192;                    // 64
    float* YBUF  = QKV;  // reuses QKV region after scores are done

    // N x N scratch lives in the d_out attn region until scores overwrite it
    float* AH = attn;                               // 8 x 1024 x 1024
    float* L2 = attn + (long)Bb * Nn * Nn;          // 8 x 1024 x 1024

    const long sQKVb = (long)Nn * LD;               // 2359296
    const long sNN   = (long)Nn * Nn;               // 1048576
    const long sNC   = (long)Nn * Cc;               // 786432

    // small precomputes
    build_g<<<1, 64, 0, stream>>>(cw, G);
    wdiff_k<<<(Cc * Cc + 255) / 256, 256, 0, stream>>>(w_v1, w_v2, WDIFF);

    // 1) qkv = x @ w_qkv^T  -> [8192,2304]
    gemm_abt<<<dim3(128, 36, 1), 256, 0, stream>>>(
        x, Cc, 0, 0, w_qkv, Cc, 0, 0, QKV, LD, 0, 0,
        nullptr, nullptr, 8192, 2304, Cc, 1, 1.0f, 0);

    // 2) attn_hat (raw): T[b] = Qf @ Kf^T (full channel) -> AH
    gemm_abt<<<dim3(16, 16, Bb), 256, 0, stream>>>(
        QKV + 0, LD, sQKVb, 0, QKV + Cc, LD, sQKVb, 0, AH, Nn, sNN, 0,
        nullptr, nullptr, Nn, Nn, Cc, 1, 1.0f, 0);

    // 3) symmetrize + relu, degree rsqrt, scale
    sym_relu<<<32768, 256, 0, stream>>>(AH);
    deg_dinv<<<Bb * Nn, 256, 0, stream>>>(AH, DINV);
    scale_ah<<<32768, 256, 0, stream>>>(AH, DINV);

    // 4) L2 = norm_ah @ norm_ah  (norm_ah symmetric => A@A^T)
    gemm_abt<<<dim3(16, 16, Bb), 256, 0, stream>>>(
        AH, Nn, sNN, 0, AH, Nn, sNN, 0, L2, Nn, sNN, 0,
        nullptr, nullptr, Nn, Nn, Nn, 1, 1.0f, 0);

    // 5) MV = L2 @ v_flat
    gemm_ab<<<dim3(16, 12, Bb), 256, 0, stream>>>(
        L2, Nn, sNN, 0, QKV + 2 * Cc, LD, sQKVb, 0, MV, Cc, sNC, 0,
        Nn, Cc, Nn, 1, 1.0f);

    // 6) IFV = spectral gate of V (circulant filter along hd)
    ifv_kernel<<<Bb * Nn, 256, 0, stream>>>(QKV, G, IFV);

    // 7) OUTB = -V @ w_v1^T + MV @ (w_v1-w_v2)^T
    gemm_abt<<<dim3(128, 12, 1), 256, 0, stream>>>(
        QKV + 2 * Cc, LD, 0, 0, w_v1, Cc, 0, 0, OUTB, Cc, 0, 0,
        nullptr, nullptr, 8192, Cc, Cc, 1, -1.0f, 0);
    gemm_abt<<<dim3(128, 12, 1), 256, 0, stream>>>(
        MV, Cc, 0, 0, WDIFF, Cc, 0, 0, OUTB, Cc, 0, 0,
        nullptr, nullptr, 8192, Cc, Cc, 1, 1.0f, 1);

    // 8) per-head scores (scaled) -> attn region (overwrites AH/L2 scratch)
    gemm_abt<<<dim3(16, 16, Bb * Hh), 256, 0, stream>>>(
        QKV + 0, LD, sQKVb, HD, QKV + Cc, LD, sQKVb, HD,
        attn, Nn, (long)Hh * sNN, sNN,
        nullptr, nullptr, Nn, Nn, HD, Hh, 0.125f, 0);

    // 9) softmax rows in-place
    softmax_rows<<<Bb * Hh * Nn, 256, 0, stream>>>(attn);

    // 10) Y = attn @ IFV (per head) -> YBUF (aliases QKV; Q/K/V all dead now)
    gemm_ab<<<dim3(16, 1, Bb * Hh), 256, 0, stream>>>(
        attn, Nn, (long)Hh * sNN, sNN, IFV, Cc, sNC, HD,
        YBUF, Cc, sNC, HD, Nn, HD, Nn, Hh, 1.0f);

    // 11) out = Y @ w_proj^T + b_proj + OUTB
    gemm_abt<<<dim3(128, 12, 1), 256, 0, stream>>>(
        YBUF, Cc, 0, 0, w_proj, Cc, 0, 0, out, Cc, 0, 0,
        OUTB, b_proj, 8192, Cc, Cc, 1, 1.0f, 0);
}